// Round 4
// baseline (425.155 us; speedup 1.0000x reference)
//
#include <hip/hip_runtime.h>
#include <hip/hip_bf16.h>

typedef __attribute__((ext_vector_type(4))) float f32x4;
typedef __attribute__((ext_vector_type(8))) __bf16 bf16x8;
typedef __attribute__((ext_vector_type(4))) __bf16 bf16x4;
typedef unsigned long long u64;

#define DIMQ 512
#define NSEQ 4096
#define NHEAD 16
#define HDIM 32
#define SCALE_QK 0.17677669529663687f

__device__ __forceinline__ void gload16(void* lds, const void* g) {
  __builtin_amdgcn_global_load_lds(
      (const __attribute__((address_space(1))) void*)g,
      (__attribute__((address_space(3))) void*)lds, 16, 0, 0);
}

// ---------------- conversion kernels ----------------

__global__ __launch_bounds__(256) void k_cvt_bf16(const float* __restrict__ in,
                                                  __bf16* __restrict__ out) {
  int i = blockIdx.x * 256 + threadIdx.x;
  float4 v = reinterpret_cast<const float4*>(in)[i];
  bf16x4 o;
  o.x = (__bf16)v.x; o.y = (__bf16)v.y; o.z = (__bf16)v.z; o.w = (__bf16)v.w;
  reinterpret_cast<bf16x4*>(out)[i] = o;
}

// in: fp32 [512][Nc]  ->  out: bf16 [Nc][512]  (transpose via LDS tile)
__global__ __launch_bounds__(256) void k_cvtT(const float* __restrict__ in,
                                              __bf16* __restrict__ out, int Nc) {
  __shared__ __bf16 t[64][72];
  int k0 = blockIdx.y * 64, n0 = blockIdx.x * 64;
  int c = threadIdx.x & 63, rr = threadIdx.x >> 6;
#pragma unroll
  for (int i = 0; i < 16; ++i) {
    int r = rr * 16 + i;
    t[r][c] = (__bf16)in[(size_t)(k0 + r) * Nc + n0 + c];
  }
  __syncthreads();
#pragma unroll
  for (int i = 0; i < 16; ++i) {
    int r = rr * 16 + i;
    out[(size_t)(n0 + r) * 512 + k0 + c] = t[c][r];
  }
}

// int32 mask [4096][4096] -> bit mask [4096][64] u64 (bit j of word w = mask[row][w*64+j])
__global__ __launch_bounds__(256) void k_maskbits(const int* __restrict__ mask,
                                                  u64* __restrict__ bits) {
  int row = blockIdx.x;
  int l = threadIdx.x & 63, w = threadIdx.x >> 6;
  const int* mr = mask + (size_t)row * NSEQ;
  for (int t = w; t < 64; t += 4) {
    u64 b = __ballot(mr[t * 64 + l] != 0);
    if (l == 0) bits[(size_t)row * 64 + t] = b;
  }
}

// ---------------- shared GEMM main loop (m97-style, swizzled gload_lds) ----------------
__device__ __forceinline__ void gemm_mainloop(const __bf16* __restrict__ A,
                                              const __bf16* __restrict__ Bt,
                                              int m0, int n0,
                                              __bf16* As, __bf16* Bs,
                                              f32x4 acc[4][4]) {
  const int tid = threadIdx.x, l = tid & 63, w = tid >> 6;
  const int wr = w >> 1, wc = w & 1;
  for (int kt = 0; kt < DIMQ; kt += 64) {
    __syncthreads();
#pragma unroll
    for (int it = 0; it < 4; ++it) {
      int c = it * 256 + tid;
      int row = c >> 3, j = c & 7, js = j ^ (row & 7);
      gload16(As + (size_t)(it * 256 + w * 64) * 8,
              A + (size_t)(m0 + row) * DIMQ + kt + js * 8);
      gload16(Bs + (size_t)(it * 256 + w * 64) * 8,
              Bt + (size_t)(n0 + row) * DIMQ + kt + js * 8);
    }
    __syncthreads();
#pragma unroll
    for (int kk = 0; kk < 2; ++kk) {
      bf16x8 a[4], b[4];
#pragma unroll
      for (int mt = 0; mt < 4; ++mt) {
        int row = wr * 64 + mt * 16 + (l & 15);
        int g = (kk * 4 + (l >> 4)) ^ (row & 7);
        a[mt] = *reinterpret_cast<const bf16x8*>((const char*)As + row * 128 + g * 16);
      }
#pragma unroll
      for (int nt = 0; nt < 4; ++nt) {
        int row = wc * 64 + nt * 16 + (l & 15);
        int g = (kk * 4 + (l >> 4)) ^ (row & 7);
        b[nt] = *reinterpret_cast<const bf16x8*>((const char*)Bs + row * 128 + g * 16);
      }
#pragma unroll
      for (int mt = 0; mt < 4; ++mt)
#pragma unroll
        for (int nt = 0; nt < 4; ++nt)
          acc[mt][nt] = __builtin_amdgcn_mfma_f32_16x16x32_bf16(a[mt], b[nt], acc[mt][nt], 0, 0, 0);
    }
  }
}

// ---------------- QKV GEMM (epilogue scatters to head layout, V transposed) ----------------
__global__ __launch_bounds__(256) void k_gemm_qkv(const __bf16* __restrict__ A,
                                                  const __bf16* __restrict__ Bt,
                                                  __bf16* __restrict__ Qh,
                                                  __bf16* __restrict__ Kh,
                                                  __bf16* __restrict__ VT) {
  __shared__ __bf16 As[128 * 64], Bs[128 * 64];
  f32x4 acc[4][4] = {};
  const int l = threadIdx.x & 63, w = threadIdx.x >> 6, wr = w >> 1, wc = w & 1;
  const int m0 = blockIdx.y * 128, n0 = blockIdx.x * 128;
  gemm_mainloop(A, Bt, m0, n0, As, Bs, acc);
#pragma unroll
  for (int nt = 0; nt < 4; ++nt) {
    int n = n0 + wc * 64 + nt * 16 + (l & 15);
    int sec = n >> 9;           // 0=q 1=k 2=v
    int hh = (n >> 5) & 15;     // head
    int d = n & 31;             // dim in head
#pragma unroll
    for (int mt = 0; mt < 4; ++mt) {
      int m = m0 + wr * 64 + mt * 16 + (l >> 4) * 4;
      int bb = m >> 12, nn = m & 4095;
      size_t bh = (size_t)bb * NHEAD + hh;
      f32x4 v = acc[mt][nt];
      if (sec == 0) {
        __bf16* p = Qh + (bh * NSEQ + nn) * HDIM + d;
        p[0] = (__bf16)v[0]; p[HDIM] = (__bf16)v[1];
        p[2 * HDIM] = (__bf16)v[2]; p[3 * HDIM] = (__bf16)v[3];
      } else if (sec == 1) {
        __bf16* p = Kh + (bh * NSEQ + nn) * HDIM + d;
        p[0] = (__bf16)v[0]; p[HDIM] = (__bf16)v[1];
        p[2 * HDIM] = (__bf16)v[2]; p[3 * HDIM] = (__bf16)v[3];
      } else {
        bf16x4 o;
        o.x = (__bf16)v[0]; o.y = (__bf16)v[1]; o.z = (__bf16)v[2]; o.w = (__bf16)v[3];
        *reinterpret_cast<bf16x4*>(VT + (bh * HDIM + d) * NSEQ + nn) = o;
      }
    }
  }
}

// ---------------- fused masked flash attention ----------------
// grid (32 q-tiles, 32 bh), 256 thr. Wave w owns 32 q rows. KV tile = 64.
__global__ __launch_bounds__(256) void k_attn(const __bf16* __restrict__ Qh,
                                              const __bf16* __restrict__ Kh,
                                              const __bf16* __restrict__ VT,
                                              const u64* __restrict__ mbits,
                                              __bf16* __restrict__ O) {
  __shared__ __bf16 Ks[64 * 32];
  __shared__ __bf16 Vs[32 * 64];
  __shared__ __bf16 Ps[4][32 * 64];
  const int l = threadIdx.x & 63, w = threadIdx.x >> 6;
  const int bh = blockIdx.y;
  const int q0 = blockIdx.x * 128 + w * 32;
  const __bf16* Qb = Qh + (size_t)bh * NSEQ * HDIM;
  const __bf16* Kb = Kh + (size_t)bh * NSEQ * HDIM;
  const __bf16* Vb = VT + (size_t)bh * HDIM * NSEQ;  // [32][4096]

  bf16x8 qf[2];
#pragma unroll
  for (int rt = 0; rt < 2; ++rt)
    qf[rt] = *reinterpret_cast<const bf16x8*>(
        Qb + (size_t)(q0 + rt * 16 + (l & 15)) * HDIM + (l >> 4) * 8);

  f32x4 acc[2][2] = {};
  float mrow[2][4], lrow[2][4];
#pragma unroll
  for (int rt = 0; rt < 2; ++rt)
#pragma unroll
    for (int r = 0; r < 4; ++r) { mrow[rt][r] = -1e30f; lrow[rt][r] = 0.f; }

  for (int kv = 0; kv < NSEQ / 64; ++kv) {
    __syncthreads();
    {
      int c = threadIdx.x;
      int rowK = c >> 2, jK = c & 3, jsK = jK ^ (rowK & 3);
      gload16(Ks + (size_t)(w * 64) * 8,
              Kb + (size_t)(kv * 64 + rowK) * HDIM + jsK * 8);
      int rowV = c >> 3, jV = c & 7, jsV = jV ^ (rowV & 7);
      gload16(Vs + (size_t)(w * 64) * 8,
              Vb + (size_t)rowV * NSEQ + kv * 64 + jsV * 8);
    }
    __syncthreads();

    bf16x8 kf[4];
#pragma unroll
    for (int f = 0; f < 4; ++f) {
      int row = f * 16 + (l & 15);
      int g = (l >> 4) ^ (row & 3);
      kf[f] = *reinterpret_cast<const bf16x8*>((const char*)Ks + row * 64 + g * 16);
    }
    bf16x8 vf[2][2];
#pragma unroll
    for (int jj = 0; jj < 2; ++jj)
#pragma unroll
      for (int dt = 0; dt < 2; ++dt) {
        int row = dt * 16 + (l & 15);
        int g = (jj * 4 + (l >> 4)) ^ (row & 7);
        vf[jj][dt] = *reinterpret_cast<const bf16x8*>((const char*)Vs + row * 128 + g * 16);
      }

#pragma unroll
    for (int rt = 0; rt < 2; ++rt) {
      f32x4 s[4];
      const f32x4 z = {0.f, 0.f, 0.f, 0.f};
#pragma unroll
      for (int f = 0; f < 4; ++f)
        s[f] = __builtin_amdgcn_mfma_f32_16x16x32_bf16(qf[rt], kf[f], z, 0, 0, 0);

      int rbase = q0 + rt * 16 + (l >> 4) * 4;
      u64 mw[4];
#pragma unroll
      for (int r = 0; r < 4; ++r) mw[r] = mbits[(size_t)(rbase + r) * 64 + kv];

      float sv[4][4], tmax[4];
#pragma unroll
      for (int r = 0; r < 4; ++r) tmax[r] = -1e30f;
#pragma unroll
      for (int f = 0; f < 4; ++f)
#pragma unroll
        for (int r = 0; r < 4; ++r) {
          float x = ((mw[r] >> (f * 16 + (l & 15))) & 1) ? s[f][r] * SCALE_QK : -1e30f;
          sv[f][r] = x;
          tmax[r] = fmaxf(tmax[r], x);
        }
#pragma unroll
      for (int r = 0; r < 4; ++r) {
        float t = tmax[r];
        t = fmaxf(t, __shfl_xor(t, 1));
        t = fmaxf(t, __shfl_xor(t, 2));
        t = fmaxf(t, __shfl_xor(t, 4));
        t = fmaxf(t, __shfl_xor(t, 8));
        float mo = mrow[rt][r];
        float mn = fmaxf(mo, t);
        float fac = __expf(mo - mn);
        mrow[rt][r] = mn;
        int prow = rt * 16 + (l >> 4) * 4 + r;
        int swz = (prow & 7) << 4;
        float ps = 0.f;
#pragma unroll
        for (int f = 0; f < 4; ++f) {
          float p = __expf(sv[f][r] - mn);
          ps += p;
          int byte = (prow * 128 + (f * 16 + (l & 15)) * 2) ^ swz;
          *reinterpret_cast<__bf16*>((char*)Ps[w] + byte) = (__bf16)p;
        }
        lrow[rt][r] = lrow[rt][r] * fac + ps;
#pragma unroll
        for (int dt = 0; dt < 2; ++dt) acc[rt][dt][r] *= fac;
      }
    }

#pragma unroll
    for (int rt = 0; rt < 2; ++rt)
#pragma unroll
      for (int jj = 0; jj < 2; ++jj) {
        int prow = rt * 16 + (l & 15);
        int byte = (prow * 128 + jj * 64 + (l >> 4) * 16) ^ ((prow & 7) << 4);
        bf16x8 pf = *reinterpret_cast<const bf16x8*>((const char*)Ps[w] + byte);
#pragma unroll
        for (int dt = 0; dt < 2; ++dt)
          acc[rt][dt] = __builtin_amdgcn_mfma_f32_16x16x32_bf16(pf, vf[jj][dt], acc[rt][dt], 0, 0, 0);
      }
  }

  const int bb = bh >> 4, hh = bh & 15;
#pragma unroll
  for (int rt = 0; rt < 2; ++rt)
#pragma unroll
    for (int r = 0; r < 4; ++r) {
      float ls = lrow[rt][r];
      ls += __shfl_xor(ls, 1);
      ls += __shfl_xor(ls, 2);
      ls += __shfl_xor(ls, 4);
      ls += __shfl_xor(ls, 8);
      float inv = 1.f / ls;
      int qrow = q0 + rt * 16 + (l >> 4) * 4 + r;
#pragma unroll
      for (int dt = 0; dt < 2; ++dt)
        O[((size_t)bb * NSEQ + qrow) * DIMQ + hh * HDIM + dt * 16 + (l & 15)] =
            (__bf16)(acc[rt][dt][r] * inv);
    }
}

// ---------------- output projection GEMM (fp32 output!) ----------------
__global__ __launch_bounds__(256) void k_gemm_proj(const __bf16* __restrict__ A,
                                                   const __bf16* __restrict__ Bt,
                                                   float* __restrict__ Out) {
  __shared__ __bf16 As[128 * 64], Bs[128 * 64];
  f32x4 acc[4][4] = {};
  const int l = threadIdx.x & 63, w = threadIdx.x >> 6, wr = w >> 1, wc = w & 1;
  const int m0 = blockIdx.y * 128, n0 = blockIdx.x * 128;
  gemm_mainloop(A, Bt, m0, n0, As, Bs, acc);
#pragma unroll
  for (int nt = 0; nt < 4; ++nt) {
    int n = n0 + wc * 64 + nt * 16 + (l & 15);
#pragma unroll
    for (int mt = 0; mt < 4; ++mt) {
      int m = m0 + wr * 64 + mt * 16 + (l >> 4) * 4;
      f32x4 v = acc[mt][nt];
      float* p = Out + (size_t)m * DIMQ + n;
      p[0] = v[0]; p[DIMQ] = v[1];
      p[2 * DIMQ] = v[2]; p[3 * DIMQ] = v[3];
    }
  }
}

// ---------------- launcher ----------------
extern "C" void kernel_launch(void* const* d_in, const int* in_sizes, int n_in,
                              void* d_out, int out_size, void* d_ws, size_t ws_size,
                              hipStream_t stream) {
  (void)in_sizes; (void)n_in; (void)out_size; (void)ws_size;
  const float* batch  = (const float*)d_in[0];
  const float* w_qkv  = (const float*)d_in[1];
  const float* w_proj = (const float*)d_in[2];
  const int*   cmask  = (const int*)d_in[3];

  __bf16* Abf = (__bf16*)d_ws;                       // 8192*512 bf16
  __bf16* WqT = Abf + (size_t)8192 * 512;            // 1536*512
  __bf16* WpT = WqT + (size_t)1536 * 512;            // 512*512
  u64*    mb  = (u64*)(WpT + (size_t)512 * 512);     // 4096*64 u64
  __bf16* Qh  = (__bf16*)(mb + (size_t)4096 * 64);   // 32*4096*32
  __bf16* Kh  = Qh + (size_t)32 * NSEQ * HDIM;
  __bf16* VT  = Kh + (size_t)32 * NSEQ * HDIM;
  __bf16* Obf = VT + (size_t)32 * NSEQ * HDIM;       // 8192*512

  k_cvt_bf16<<<4096, 256, 0, stream>>>(batch, Abf);
  k_cvtT<<<dim3(24, 8), 256, 0, stream>>>(w_qkv, WqT, 1536);
  k_cvtT<<<dim3(8, 8), 256, 0, stream>>>(w_proj, WpT, 512);
  k_maskbits<<<4096, 256, 0, stream>>>(cmask, mb);
  k_gemm_qkv<<<dim3(12, 64), 256, 0, stream>>>(Abf, WqT, Qh, Kh, VT);
  k_attn<<<dim3(32, 32), 256, 0, stream>>>(Qh, Kh, VT, mb, Obf);
  k_gemm_proj<<<dim3(4, 64), 256, 0, stream>>>(Obf, WpT, (float*)d_out);
}